// Round 1
// baseline (11658.337 us; speedup 1.0000x reference)
//
#include <hip/hip_runtime.h>
#include <math.h>

#define DIMD 240
#define SEQ  1024
#define NB   240
#define KT   16
#define SC   32

// K1: MT[f][e] = sum_d Wk[d][e] * Wv[d][f]   (i.e. M = Wk^T Wv, stored transposed [f][e])
__global__ __launch_bounds__(256) void k_matM(const float* __restrict__ Wk,
                                              const float* __restrict__ Wv,
                                              float* __restrict__ MT) {
  const int f = blockIdx.x;
  const int e = threadIdx.x;
  if (e >= DIMD) return;
  float acc = 0.f;
#pragma unroll 4
  for (int d = 0; d < DIMD; ++d)
    acc += Wk[d * DIMD + e] * Wv[d * DIMD + f];
  MT[f * DIMD + e] = acc;
}

// K2: per-batch diag[b][s] = dec * sum_f (x[b,s]@M)[f] * Xcum[b,s][f]
__global__ __launch_bounds__(256) void k_diag(const float* __restrict__ x,
                                              const float* __restrict__ MT,
                                              const float* __restrict__ mask,
                                              float* __restrict__ diag) {
  __shared__ float Xc[SC][244];
  __shared__ float Tc[SC][244];
  __shared__ float Mt[DIMD][20];
  const int b    = blockIdx.x;
  const int tid  = threadIdx.x;
  const int tx   = tid & 15, ty = tid >> 4;
  const int lane = tid & 63, wid = tid >> 6;
  const float dec = mask[0];  // tril(0.9): mask[0][0] = 0.9

  float xcum0 = 0.f, xcum1 = 0.f, xcum2 = 0.f, xcum3 = 0.f;

  for (int s0 = 0; s0 < SEQ; s0 += SC) {
    __syncthreads();
    // stage 32 rows of x[b] into LDS
    for (int i = tid; i < SC * 60; i += 256) {
      int r = i / 60, c4 = (i % 60) * 4;
      *reinterpret_cast<float4*>(&Xc[r][c4]) =
          *reinterpret_cast<const float4*>(&x[((size_t)b * SEQ + s0 + r) * DIMD + c4]);
    }
    __syncthreads();

    float acc[2][15];
#pragma unroll
    for (int q = 0; q < 2; ++q)
#pragma unroll
      for (int i = 0; i < 15; ++i) acc[q][i] = 0.f;

    for (int e0 = 0; e0 < DIMD; e0 += KT) {
      __syncthreads();
      for (int i = tid; i < DIMD * 4; i += 256) {
        int c = i >> 2, seg = (i & 3) << 2;
        *reinterpret_cast<float4*>(&Mt[c][seg]) =
            *reinterpret_cast<const float4*>(&MT[c * DIMD + e0 + seg]);
      }
      __syncthreads();
#pragma unroll
      for (int kk = 0; kk < KT; kk += 4) {
        const float4 xa = *reinterpret_cast<const float4*>(&Xc[ty * 2 + 0][e0 + kk]);
        const float4 xb = *reinterpret_cast<const float4*>(&Xc[ty * 2 + 1][e0 + kk]);
#pragma unroll
        for (int i = 0; i < 15; ++i) {
          const float4 wv = *reinterpret_cast<const float4*>(&Mt[tx + (i << 4)][kk]);
          acc[0][i] += xa.x * wv.x + xa.y * wv.y + xa.z * wv.z + xa.w * wv.w;
          acc[1][i] += xb.x * wv.x + xb.y * wv.y + xb.z * wv.z + xb.w * wv.w;
        }
      }
    }
    // write T = x@M for this chunk
#pragma unroll
    for (int q = 0; q < 2; ++q)
#pragma unroll
      for (int i = 0; i < 15; ++i)
        Tc[ty * 2 + q][tx + (i << 4)] = acc[q][i];
    __syncthreads();

    // phase C: running prefix over s, dot(T, Xcum), wave-level reduce.
    // every wave maintains the full xcum (f = lane + 64j); wave w owns rows [w*8, w*8+8)
    for (int r = 0; r < SC; ++r) {
      xcum0 += Xc[r][lane];
      xcum1 += Xc[r][lane + 64];
      xcum2 += Xc[r][lane + 128];
      if (lane < 48) xcum3 += Xc[r][lane + 192];
      if ((r >> 3) == wid) {
        float p = Tc[r][lane] * xcum0 + Tc[r][lane + 64] * xcum1 + Tc[r][lane + 128] * xcum2;
        if (lane < 48) p += Tc[r][lane + 192] * xcum3;
#pragma unroll
        for (int off = 32; off; off >>= 1) p += __shfl_down(p, off);
        if (lane == 0) diag[(size_t)b * SEQ + s0 + r] = dec * p;
      }
    }
  }
}

// K3: out[i,s,m] = sum_j (Wx x)[j] * sigmoid((Wg x)[j]) * diag[j][s] * Wo[m][j] + bo[m]
__global__ __launch_bounds__(256) void k_main(const float* __restrict__ x,
                                              const float* __restrict__ Wx,
                                              const float* __restrict__ Wg,
                                              const float* __restrict__ Wo,
                                              const float* __restrict__ bo,
                                              const float* __restrict__ diag,
                                              float* __restrict__ out) {
  __shared__ float Xs[64][244];
  __shared__ float Wa[DIMD][20];
  __shared__ float Wb[DIMD][20];
  const int tid = threadIdx.x;
  const int tx  = tid & 15, ty = tid >> 4;
  const size_t row0 = (size_t)blockIdx.x * 64;
  const int s0 = (int)(row0 & (SEQ - 1));

  // stage 64 rows of x
  for (int i = tid; i < 64 * 60; i += 256) {
    int r = i / 60, c4 = (i % 60) * 4;
    *reinterpret_cast<float4*>(&Xs[r][c4]) =
        *reinterpret_cast<const float4*>(&x[(row0 + r) * DIMD + c4]);
  }

  float accA[4][15], accG[4][15];
#pragma unroll
  for (int q = 0; q < 4; ++q)
#pragma unroll
    for (int i = 0; i < 15; ++i) { accA[q][i] = 0.f; accG[q][i] = 0.f; }

  for (int k0 = 0; k0 < DIMD; k0 += KT) {
    __syncthreads();
    for (int i = tid; i < DIMD * 4; i += 256) {
      int c = i >> 2, seg = (i & 3) << 2;
      *reinterpret_cast<float4*>(&Wa[c][seg]) =
          *reinterpret_cast<const float4*>(&Wx[c * DIMD + k0 + seg]);
      *reinterpret_cast<float4*>(&Wb[c][seg]) =
          *reinterpret_cast<const float4*>(&Wg[c * DIMD + k0 + seg]);
    }
    __syncthreads();
#pragma unroll
    for (int kk = 0; kk < KT; kk += 4) {
      float4 xv[4];
#pragma unroll
      for (int q = 0; q < 4; ++q)
        xv[q] = *reinterpret_cast<const float4*>(&Xs[ty * 4 + q][k0 + kk]);
#pragma unroll
      for (int i = 0; i < 15; ++i) {
        const int c = tx + (i << 4);
        const float4 wa = *reinterpret_cast<const float4*>(&Wa[c][kk]);
        const float4 wb = *reinterpret_cast<const float4*>(&Wb[c][kk]);
#pragma unroll
        for (int q = 0; q < 4; ++q) {
          accA[q][i] += xv[q].x * wa.x + xv[q].y * wa.y + xv[q].z * wa.z + xv[q].w * wa.w;
          accG[q][i] += xv[q].x * wb.x + xv[q].y * wb.y + xv[q].z * wb.z + xv[q].w * wb.w;
        }
      }
    }
  }
  __syncthreads();
  // Y = A * sigmoid(G) * diag[c][s], overwrite Xs with Y
#pragma unroll
  for (int q = 0; q < 4; ++q) {
    const int r = ty * 4 + q;
    const int s = s0 + r;
#pragma unroll
    for (int i = 0; i < 15; ++i) {
      const int c  = tx + (i << 4);
      const float dv = diag[(size_t)c * SEQ + s];
      const float g  = 1.f / (1.f + __expf(-accG[q][i]));
      Xs[r][c] = accA[q][i] * g * dv;
    }
  }
  __syncthreads();

  float accO[4][15];
#pragma unroll
  for (int q = 0; q < 4; ++q)
#pragma unroll
    for (int i = 0; i < 15; ++i) accO[q][i] = 0.f;

  for (int k0 = 0; k0 < DIMD; k0 += KT) {
    __syncthreads();
    for (int i = tid; i < DIMD * 4; i += 256) {
      int c = i >> 2, seg = (i & 3) << 2;
      *reinterpret_cast<float4*>(&Wa[c][seg]) =
          *reinterpret_cast<const float4*>(&Wo[c * DIMD + k0 + seg]);
    }
    __syncthreads();
#pragma unroll
    for (int kk = 0; kk < KT; kk += 4) {
      float4 yv[4];
#pragma unroll
      for (int q = 0; q < 4; ++q)
        yv[q] = *reinterpret_cast<const float4*>(&Xs[ty * 4 + q][k0 + kk]);
#pragma unroll
      for (int i = 0; i < 15; ++i) {
        const int m = tx + (i << 4);
        const float4 wo = *reinterpret_cast<const float4*>(&Wa[m][kk]);
#pragma unroll
        for (int q = 0; q < 4; ++q)
          accO[q][i] += yv[q].x * wo.x + yv[q].y * wo.y + yv[q].z * wo.z + yv[q].w * wo.w;
      }
    }
  }

#pragma unroll
  for (int q = 0; q < 4; ++q) {
    const size_t r = row0 + ty * 4 + q;
#pragma unroll
    for (int i = 0; i < 15; ++i) {
      const int m = tx + (i << 4);
      out[r * DIMD + m] = accO[q][i] + bo[m];
    }
  }
}

extern "C" void kernel_launch(void* const* d_in, const int* in_sizes, int n_in,
                              void* d_out, int out_size, void* d_ws, size_t ws_size,
                              hipStream_t stream) {
  const float* x    = (const float*)d_in[0];
  const float* Wx   = (const float*)d_in[1];
  const float* Wk   = (const float*)d_in[2];
  const float* Wv   = (const float*)d_in[3];
  const float* Wg   = (const float*)d_in[4];
  const float* Wo   = (const float*)d_in[5];
  const float* bo   = (const float*)d_in[6];
  const float* mask = (const float*)d_in[7];
  float* out = (float*)d_out;

  float* MT   = (float*)d_ws;          // 240*240 f32 = 230 KB
  float* diag = MT + DIMD * DIMD;      // 240*1024 f32 = 983 KB  (ws use ~1.2 MB total)

  hipLaunchKernelGGL(k_matM, dim3(DIMD), dim3(256), 0, stream, Wk, Wv, MT);
  hipLaunchKernelGGL(k_diag, dim3(NB), dim3(256), 0, stream, x, MT, mask, diag);
  hipLaunchKernelGGL(k_main, dim3((NB * SEQ) / 64), dim3(256), 0, stream,
                     x, Wx, Wg, Wo, bo, diag, out);
}